// Round 5
// baseline (442.751 us; speedup 1.0000x reference)
//
#include <hip/hip_runtime.h>
#include <hip/hip_bf16.h>
#include <cstdint>
#include <cstddef>

#define B_   2
#define N_   2048
#define D_   2048
#define H_   16
#define HD_  128
#define C_   128
#define NC_  16
#define M_   4096   // B_*N_
#define QKVG_ 8192  // fused projection width: q|k|v|gate

typedef __attribute__((ext_vector_type(8))) short bf16x8;
typedef __attribute__((ext_vector_type(4))) float f32x4;
typedef __attribute__((ext_vector_type(16))) float f32x16;

__device__ __forceinline__ uint16_t f2bf(float f){
  __hip_bfloat16 h = __float2bfloat16(f);
  return *reinterpret_cast<uint16_t*>(&h);
}
__device__ __forceinline__ float bf2f(uint16_t u){
  union { uint32_t i; float f; } v; v.i = ((uint32_t)u) << 16; return v.f;
}

// async global->LDS, 16B per lane. LDS dest must be wave-uniform base + lane*16.
__device__ __forceinline__ void async16(const uint16_t* g, uint16_t* l){
  __builtin_amdgcn_global_load_lds(
      (const __attribute__((address_space(1))) void*)g,
      (__attribute__((address_space(3))) void*)l, 16, 0, 0);
}

// [128][128] attention-tile swizzle (unchanged, verified-correct kernels use it)
__device__ __forceinline__ int swz(int row, int c){
  return row*128 + ((((c >> 3) ^ row) & 15) << 3) + (c & 7);
}

// ---------------------------------------------------------------- cast fp32->bf16
__global__ __launch_bounds__(256) void cast_kernel(
    const float* __restrict__ x, uint16_t* __restrict__ y)
{
  int i = (blockIdx.x*256 + threadIdx.x)*4;
  float4 f = *(const float4*)(x + i);
  ushort4 u;
  u.x = f2bf(f.x); u.y = f2bf(f.y); u.z = f2bf(f.z); u.w = f2bf(f.w);
  *(ushort4*)(y + i) = u;
}

// ---------------------------------------- all weight prep in ONE launch (grid.z)
__global__ __launch_bounds__(256)
void prep_weights(const float* __restrict__ Wq, const float* __restrict__ Wk,
                  const float* __restrict__ Wv, const float* __restrict__ Wo,
                  const float* __restrict__ Wg2, const float* __restrict__ Wg1,
                  uint16_t* __restrict__ WT, uint16_t* __restrict__ WoT,
                  uint16_t* __restrict__ Wg2T, uint16_t* __restrict__ Wg1b)
{
  const int z = blockIdx.z;
  const int tx = threadIdx.x & 31;
  const int ty = threadIdx.x >> 5;   // 0..7
  __shared__ uint16_t tile[32][33];

  if (z == 5){                       // straight cast Wg1
    if (blockIdx.x >= 4) return;
    const int r0 = blockIdx.y*32, c0 = blockIdx.x*32;
    #pragma unroll
    for (int rr = 0; rr < 4; ++rr){
      int r = r0 + ty + rr*8;
      Wg1b[(size_t)r*HD_ + c0 + tx] = f2bf(Wg1[(size_t)r*HD_ + c0 + tx]);
    }
    return;
  }

  const float* src; uint16_t* dst; int R, Cc;
  if (z < 3)      { src = (z==0)?Wq:(z==1)?Wk:Wv; dst = WT + (size_t)z*D_*D_; R = D_; Cc = D_; }
  else if (z == 3){ src = Wo;  dst = WoT;  R = D_;  Cc = D_; }
  else            { if (blockIdx.y >= 4) return;
                    src = Wg2; dst = Wg2T; R = HD_; Cc = D_; }

  const int r0 = blockIdx.y*32, c0 = blockIdx.x*32;
  #pragma unroll
  for (int rr = 0; rr < 4; ++rr){
    int r = ty + rr*8;
    tile[r][tx] = f2bf(src[(size_t)(r0 + r)*Cc + c0 + tx]);
  }
  __syncthreads();
  #pragma unroll
  for (int rr = 0; rr < 4; ++rr){
    int r = ty + rr*8;
    dst[(size_t)(c0 + r)*R + r0 + tx] = tile[tx][r];
  }
}

// ------------------------------------------------- GEMM v2 (kept for small-K Wg GEMM)
template<int ACT, int OUTBF>
__global__ __launch_bounds__(256)
void gemm_bt2(const uint16_t* __restrict__ A, const uint16_t* __restrict__ Bt,
              void* __restrict__ Cout, int M, int Ncols, int K, int klen)
{
  __shared__ __align__(16) uint16_t As[128*64];
  __shared__ __align__(16) uint16_t Bs[128*64];
  const int t    = threadIdx.x;
  const int lane = t & 63, wave = t >> 6;
  const int wm = wave >> 1, wn = wave & 1;
  const int row0 = wm*64, col0 = wn*64;
  const int lm = lane & 31, lh = lane >> 5;

  const uint16_t* Ap = A  + (size_t)(blockIdx.y*128)*K;
  const uint16_t* Bp = Bt + (size_t)(blockIdx.x*128)*K;
  const int kbeg = blockIdx.z * klen;

  f32x16 acc[2][2];
  #pragma unroll
  for (int i = 0; i < 2; ++i)
    #pragma unroll
    for (int j = 0; j < 2; ++j)
      #pragma unroll
      for (int r = 0; r < 16; ++r) acc[i][j][r] = 0.f;

  const int srow = t >> 3;
  const int gch  = (t & 7) ^ (srow & 7);
  const size_t aoff0 = (size_t)srow*K + gch*8;

  for (int k0 = kbeg; k0 < kbeg + klen; k0 += 64){
    #pragma unroll
    for (int c = 0; c < 4; ++c){
      async16(Ap + (size_t)(c*32)*K + aoff0 + k0, As + c*2048 + t*8);
      async16(Bp + (size_t)(c*32)*K + aoff0 + k0, Bs + c*2048 + t*8);
    }
    __syncthreads();
    #pragma unroll
    for (int kh = 0; kh < 4; ++kh){
      bf16x8 af[2], bfr[2];
      const int ch = kh*2 + lh;
      #pragma unroll
      for (int i = 0; i < 2; ++i){
        int r = row0 + i*32 + lm;
        af[i] = *(const bf16x8*)(As + r*64 + ((ch ^ (r & 7)) << 3));
      }
      #pragma unroll
      for (int j = 0; j < 2; ++j){
        int r = col0 + j*32 + lm;
        bfr[j] = *(const bf16x8*)(Bs + r*64 + ((ch ^ (r & 7)) << 3));
      }
      #pragma unroll
      for (int i = 0; i < 2; ++i)
        #pragma unroll
        for (int j = 0; j < 2; ++j)
          acc[i][j] = __builtin_amdgcn_mfma_f32_32x32x16_bf16(af[i], bfr[j], acc[i][j], 0, 0, 0);
    }
    __syncthreads();
  }

  const int mode = (ACT == 3) ? ((blockIdx.x < 48) ? 1 : 2) : ACT;
  uint16_t* outb = (uint16_t*)Cout;
  float*    outf = (float*)Cout + (OUTBF ? 0 : (size_t)blockIdx.z*M*Ncols);
  #pragma unroll
  for (int i = 0; i < 2; ++i){
    #pragma unroll
    for (int j = 0; j < 2; ++j){
      #pragma unroll
      for (int r = 0; r < 16; ++r){
        int row = blockIdx.y*128 + row0 + i*32 + (r & 3) + 8*(r >> 2) + 4*lh;
        int col = blockIdx.x*128 + col0 + j*32 + lm;
        float v = acc[i][j][r];
        if (mode == 1)      v = v / (1.f + __expf(-v));
        else if (mode == 2) v = 1.f / (1.f + __expf(-v));
        size_t off = (size_t)row*Ncols + col;
        if (OUTBF) outb[off] = f2bf(v);
        else       outf[off] = v;
      }
    }
  }
}

// ============================================================ GEMM v6: 256x256
// Single-barrier-per-K-step schedule, 16x16x32 MFMA (the shape every measured
// high performer uses: m97 912, m201 1563, HK 1909 — our 32x32x16 variants all
// stuck at ~810 TF with 4 barriers + 2 lgkm-drains per step = measured ~1800
// stall cyc/step).
//   - BK=32 K-steps, ring-of-4 LDS buffers (4x16KiB A + 4x16KiB B = 128 KiB);
//     stage for K-step kt+3 issued at kt -> prefetch distance ~3 steps,
//     far beyond HBM latency.
//   - 8 waves as 2M x 4N (wave tile 128x64): 8 A-frags + 4 B-frags per step
//     (12 ds_read_b128), 32 independent 16x16x32 MFMA into acc[8][4] (f32x4).
//   - Per step sync: per-wave lgkmcnt(0) (+sched_barrier, rule #18), ONE
//     counted vmcnt(8) (never 0 until tail), ONE s_barrier. Waves skew freely
//     within the step; the barrier re-syncs once per step.
// Hazard ledger (enumerated):
//   WAR: stage(kt+3) writes buf (kt+3)&3 == (kt-1)&3. Every wave's reads of
//     tile kt-1 were drained by its own lgkmcnt(0) before the end-of-(kt-1)
//     barrier, which precedes any wave's stage(kt+3) in step kt. Safe.
//   RAW: at end of kt, stages younger than tile kt+1's last stmt are tiles
//     kt+2 (4) + kt+3 (4) = 8 -> vmcnt(8) certifies tile kt+1 exactly; the
//     following s_barrier makes it block-wide. Tail: 8 -> 4 -> 0.
// Conflict note: SQ_LDS_BANK_CONFLICT == 4.0 x (#ds_read_b128) in ALL four
// prior kernels incl. different row widths/swizzles -> wave64-b128 counting
// artifact (8 bank passes), time-free per m136. Layout is not the limiter.
template<int ACT, int OUTBF>
__global__ __launch_bounds__(512, 2)
void gemm256(const uint16_t* __restrict__ A, const uint16_t* __restrict__ Bt,
             void* __restrict__ Cout, int M, int Ncols, int K, int klen)
{
  __shared__ __align__(16) uint16_t As[4*256*32];   // 64 KiB: ring of 4
  __shared__ __align__(16) uint16_t Bs[4*256*32];   // 64 KiB
  const int t    = threadIdx.x;
  const int lane = t & 63, wave = t >> 6;
  const int wm = wave >> 2, wn = wave & 3;          // 2M x 4N wave grid
  const int lr = lane & 15, kq = lane >> 4;         // 16x16x32 operand mapping
  const int sl = (kq ^ ((lr >> 1) & 3)) << 3;       // swizzled 16B slot (bijective)

  // element offsets inside one 8192-elem buffer: row*32 + slot*8.
  // frag bases are 0 mod 16 -> (row>>1)&3 == (lr>>1)&3, so sl is frag-invariant.
  int arow[8], brow[4];
  #pragma unroll
  for (int m = 0; m < 8; ++m) arow[m] = (wm*128 + m*16 + lr)*32 + sl;
  #pragma unroll
  for (int n = 0; n < 4; ++n) brow[n] = (wn*64 + n*16 + lr)*32 + sl;

  const uint16_t* Ap = A  + (size_t)(blockIdx.y*256)*K;
  const uint16_t* Bp = Bt + (size_t)(blockIdx.x*256)*K;
  const int kbeg = blockIdx.z*klen;
  const int NTK  = klen >> 5;                       // BK=32 K-steps (NTK >= 4)

  // staging map: thread t fills LDS elems t*8..t*8+7 (row t>>2, slot t&3);
  // global chunk pre-swizzled: gch = slot ^ ((row>>1)&3)  (rule #21).
  const int gch  = (t & 3) ^ ((t >> 3) & 3);
  const size_t srcoff = (size_t)(t >> 2)*K + gch*8;
  const int ldst = t*8;

  f32x4 acc[8][4];
  #pragma unroll
  for (int m = 0; m < 8; ++m)
    #pragma unroll
    for (int n = 0; n < 4; ++n)
      #pragma unroll
      for (int r = 0; r < 4; ++r) acc[m][n][r] = 0.f;

  auto stageA = [&](int j){        // A of K-step j -> buf j&3 (2 stmts, 16 KiB)
    const size_t ko = (size_t)kbeg + (size_t)j*32;
    uint16_t* d = As + (j & 3)*8192 + ldst;
    async16(Ap + srcoff + ko, d);
    async16(Ap + (size_t)128*K + srcoff + ko, d + 4096);
  };
  auto stageB = [&](int j){
    const size_t ko = (size_t)kbeg + (size_t)j*32;
    uint16_t* d = Bs + (j & 3)*8192 + ldst;
    async16(Bp + srcoff + ko, d);
    async16(Bp + (size_t)128*K + srcoff + ko, d + 4096);
  };

  // prologue: stage K-steps 0..2 (12 stmts); vmcnt(8) certifies step 0.
  stageA(0); stageB(0);
  stageA(1); stageB(1);
  stageA(2); stageB(2);
  asm volatile("s_waitcnt vmcnt(8)" ::: "memory");
  __builtin_amdgcn_s_barrier();
  asm volatile("" ::: "memory");

  for (int kt = 0; kt < NTK; ++kt){
    const uint16_t* Ac = As + (kt & 3)*8192;
    const uint16_t* Bc = Bs + (kt & 3)*8192;

    // issue next prefetch first so the loads launch early in the step
    if (kt + 3 < NTK){ stageA(kt + 3); stageB(kt + 3); }

    bf16x8 af[8], bf[4];
    #pragma unroll
    for (int m = 0; m < 8; ++m) af[m] = *(const bf16x8*)(Ac + arow[m]);
    #pragma unroll
    for (int n = 0; n < 4; ++n) bf[n] = *(const bf16x8*)(Bc + brow[n]);
    asm volatile("s_waitcnt lgkmcnt(0)" ::: "memory");
    __builtin_amdgcn_sched_barrier(0);            // rule #18: pin MFMA below wait

    __builtin_amdgcn_s_setprio(1);
    #pragma unroll
    for (int m = 0; m < 8; ++m)
      #pragma unroll
      for (int n = 0; n < 4; ++n)
        acc[m][n] = __builtin_amdgcn_mfma_f32_16x16x32_bf16(af[m], bf[n], acc[m][n], 0, 0, 0);
    __builtin_amdgcn_s_setprio(0);

    // counted vmcnt: certify tile kt+1 exactly; single barrier per step
    if (kt + 3 < NTK)      asm volatile("s_waitcnt vmcnt(8)" ::: "memory");
    else if (kt + 2 < NTK) asm volatile("s_waitcnt vmcnt(4)" ::: "memory");
    else                   asm volatile("s_waitcnt vmcnt(0)" ::: "memory");
    __builtin_amdgcn_s_barrier();
    asm volatile("" ::: "memory");
  }

  // epilogue. 16x16x32 C/D layout: col = lane&15, row = (lane>>4)*4 + r (m89)
  const int mode = (ACT == 3) ? (((blockIdx.x << 8) < Ncols - 2048) ? 1 : 2) : ACT;
  uint16_t* outb = (uint16_t*)Cout;
  float*    outf = (float*)Cout + (OUTBF ? 0 : (size_t)blockIdx.z*M*Ncols);
  #pragma unroll
  for (int m = 0; m < 8; ++m){
    #pragma unroll
    for (int n = 0; n < 4; ++n){
      #pragma unroll
      for (int r = 0; r < 4; ++r){
        int row = blockIdx.y*256 + wm*128 + m*16 + kq*4 + r;
        int col = blockIdx.x*256 + wn*64  + n*16 + lr;
        float v = acc[m][n][r];
        if (mode == 1)      v = v / (1.f + __expf(-v));
        else if (mode == 2) v = 1.f / (1.f + __expf(-v));
        size_t off = (size_t)row*Ncols + col;
        if (OUTBF) outb[off] = f2bf(v);
        else       outf[off] = v;
      }
    }
  }
}

// ------------------------------------------------------ split-K partial add
__global__ __launch_bounds__(256)
void add_kernel(const float* __restrict__ p0, const float* __restrict__ p1,
                float* __restrict__ out)
{
  int i = (blockIdx.x*256 + threadIdx.x)*4;
  float4 a = *(const float4*)(p0 + i);
  float4 b = *(const float4*)(p1 + i);
  float4 o; o.x = a.x+b.x; o.y = a.y+b.y; o.z = a.z+b.z; o.w = a.w+b.w;
  *(float4*)(out + i) = o;
}

// ---------------------------------------------- per-chunk state contribution
__global__ __launch_bounds__(256)
void chunk_state_kernel(const uint16_t* __restrict__ qkvg,
                        const float* __restrict__ log_decay, uint16_t* __restrict__ MsumT)
{
  __shared__ __align__(16) uint16_t vT[128*128];
  __shared__ __align__(16) uint16_t kT[128*128];
  const int h = blockIdx.x, b = blockIdx.y, ic = blockIdx.z;
  const int t    = threadIdx.x;
  const int lane = t & 63, wave = t >> 6;
  const int wm = wave >> 1, wn = wave & 1;
  const int e0 = wm*64, d0 = wn*64;
  const int lr = lane & 15, kq = lane >> 4;
  const float ld = log_decay[h];
  const size_t rowbase = (size_t)b*N_ + (size_t)ic*C_;
  const uint16_t* kb = qkvg + (size_t)D_;
  const uint16_t* vb = qkvg + (size_t)2*D_;

  #pragma unroll 4
  for (int it = 0; it < 64; ++it){
    int idx = t + it*256;
    int j = idx >> 7, e = idx & 127;
    uint16_t vv = vb[(rowbase + j)*QKVG_ + h*HD_ + e];
    float kf = bf2f(kb[(rowbase + j)*QKVG_ + h*HD_ + e]) * __expf(ld * (float)(C_ - 1 - j));
    vT[swz(e, j)] = vv;
    kT[swz(e, j)] = f2bf(kf);
  }
  __syncthreads();

  const f32x4 zero = {0.f, 0.f, 0.f, 0.f};
  f32x4 acc[4][4];
  #pragma unroll
  for (int i = 0; i < 4; ++i)
    #pragma unroll
    for (int j = 0; j < 4; ++j) acc[i][j] = zero;

  #pragma unroll
  for (int kt = 0; kt < 4; ++kt){
    bf16x8 af[4], bfr[4];
    #pragma unroll
    for (int i = 0; i < 4; ++i)
      af[i]  = *(const bf16x8*)(vT + swz(e0 + i*16 + lr, kt*32 + kq*8));
    #pragma unroll
    for (int j = 0; j < 4; ++j)
      bfr[j] = *(const bf16x8*)(kT + swz(d0 + j*16 + lr, kt*32 + kq*8));
    #pragma unroll
    for (int i = 0; i < 4; ++i)
      #pragma unroll
      for (int j = 0; j < 4; ++j)
        acc[i][j] = __builtin_amdgcn_mfma_f32_16x16x32_bf16(af[i], bfr[j], acc[i][j], 0, 0, 0);
  }

  uint16_t* Mout = MsumT + (((size_t)ic*B_ + b)*H_ + h)*(size_t)(HD_*HD_);
  #pragma unroll
  for (int i = 0; i < 4; ++i)
    #pragma unroll
    for (int j = 0; j < 4; ++j)
      #pragma unroll
      for (int r = 0; r < 4; ++r)
        Mout[(size_t)(e0 + i*16 + kq*4 + r)*HD_ + d0 + j*16 + lr] = f2bf(acc[i][j][r]);
}

// -------------------------------------------------- inter-chunk state scan
__global__ __launch_bounds__(256)
void scan_kernel(const uint16_t* __restrict__ MsumT, const float* __restrict__ log_decay,
                 uint16_t* __restrict__ StT)
{
  const int h = blockIdx.x, b = blockIdx.y;
  const float ld = log_decay[h];
  const float dS = __expf(ld * (float)C_);
  const int base_e = blockIdx.z*2048;
  float cur[8];
  #pragma unroll
  for (int r = 0; r < 8; ++r) cur[r] = 0.f;
  for (int i = 0; i < NC_; ++i){
    const size_t base = (((size_t)i*B_ + b)*H_ + h)*(size_t)(HD_*HD_) + base_e;
    #pragma unroll
    for (int r = 0; r < 8; ++r){
      int idx = threadIdx.x + r*256;
      StT[base + idx] = f2bf(cur[r]);
      cur[r] = cur[r]*dS + bf2f(MsumT[base + idx]);
    }
  }
}

// ------------------------------------------------------ intra-chunk attention
__global__ __launch_bounds__(256)
void attn_kernel(const uint16_t* __restrict__ qkvg, const uint16_t* __restrict__ StT,
                 const float* __restrict__ log_decay, float* __restrict__ o_attn)
{
  __shared__ __align__(16) uint16_t Ps[128*128];
  __shared__ __align__(16) uint16_t vT[128*128];
  const int h = blockIdx.x, b = blockIdx.y, ic = blockIdx.z;
  const int t    = threadIdx.x;
  const int lane = t & 63, wave = t >> 6;
  const int wm = wave >> 1, wn = wave & 1;
  const int row0 = wm*64, col0 = wn*64;
  const int lr = lane & 15, kq = lane >> 4;
  const float ld = log_decay[h];
  const size_t rowbase = (size_t)b*N_ + (size_t)ic*C_;
  const uint16_t* qb = qkvg;
  const uint16_t* kb = qkvg + (size_t)D_;
  const uint16_t* vb = qkvg + (size_t)2*D_;

  #pragma unroll 4
  for (int it = 0; it < 64; ++it){
    int idx = t + it*256;
    int j = idx >> 7, e = idx & 127;
    vT[swz(e, j)] = vb[(rowbase + j)*QKVG_ + h*HD_ + e];
  }

  const f32x4 zero = {0.f, 0.f, 0.f, 0.f};
  f32x4 acc[4][4];
  #pragma unroll
  for (int i = 0; i < 4; ++i)
    #pragma unroll
    for (int j = 0; j < 4; ++j) acc[i][j] = zero;

  // phase A: P = (q @ k^T) ∘ Dm
  #pragma unroll
  for (int kt = 0; kt < 4; ++kt){
    bf16x8 af[4], bfr[4];
    #pragma unroll
    for (int i = 0; i < 4; ++i)
      af[i]  = *(const bf16x8*)(qb + (rowbase + row0 + i*16 + lr)*QKVG_ + h*HD_ + kt*32 + kq*8);
    #pragma unroll
    for (int j = 0; j < 4; ++j)
      bfr[j] = *(const bf16x8*)(kb + (rowbase + col0 + j*16 + lr)*QKVG_ + h*HD_ + kt*32 + kq*8);
    #pragma unroll
    for (int i = 0; i < 4; ++i)
      #pragma unroll
      for (int j = 0; j < 4; ++j)
        acc[i][j] = __builtin_amdgcn_mfma_f32_16x16x32_bf16(af[i], bfr[j], acc[i][j], 0, 0, 0);
  }
  #pragma unroll
  for (int i = 0; i < 4; ++i)
    #pragma unroll
    for (int j = 0; j < 4; ++j)
      #pragma unroll
      for (int r = 0; r < 4; ++r){
        int row = row0 + i*16 + kq*4 + r;
        int col = col0 + j*16 + lr;
        int dlt = row - col;
        float f = (dlt >= 0) ? __expf(ld * (float)dlt) : 0.f;
        Ps[swz(row, col)] = f2bf(acc[i][j][r] * f);
      }

  // phase B1: o2 = q @ S_start
  #pragma unroll
  for (int i = 0; i < 4; ++i)
    #pragma unroll
    for (int j = 0; j < 4; ++j) acc[i][j] = zero;
  const uint16_t* Sb = StT + (((size_t)ic*B_ + b)*H_ + h)*(size_t)(HD_*HD_);
  #pragma unroll
  for (int kt = 0; kt < 4; ++kt){
    bf16x8 af[4], bfr[4];
    #pragma unroll
    for (int i = 0; i < 4; ++i)
      af[i]  = *(const bf16x8*)(qb + (rowbase + row0 + i*16 + lr)*QKVG_ + h*HD_ + kt*32 + kq*8);
    #pragma unroll
    for (int j = 0; j < 4; ++j)
      bfr[j] = *(const bf16x8*)(Sb + (size_t)(col0 + j*16 + lr)*HD_ + kt*32 + kq*8);
    #pragma unroll
    for (int i = 0; i < 4; ++i)
      #pragma unroll
      for (int j = 0; j < 4; ++j)
        acc[i][j] = __builtin_amdgcn_mfma_f32_16x16x32_bf16(af[i], bfr[j], acc[i][j], 0, 0, 0);
  }
  #pragma unroll
  for (int i = 0; i < 4; ++i)
    #pragma unroll
    for (int r = 0; r < 4; ++r){
      float dqv = __expf(ld * (float)(row0 + i*16 + kq*4 + r + 1));
      #pragma unroll
      for (int j = 0; j < 4; ++j) acc[i][j][r] *= dqv;
    }

  __syncthreads();

  // phase B2: o += P @ v
  #pragma unroll
  for (int kt = 0; kt < 4; ++kt){
    bf16x8 af[4], bfr[4];
    #pragma unroll
    for (int i = 0; i < 4; ++i)
      af[i]  = *(const bf16x8*)(Ps + swz(row0 + i*16 + lr, kt*32 + kq*8));
    #pragma unroll
    for (int j = 0; j < 4; ++j)
      bfr[j] = *(const bf16x8*)(vT + swz(col0 + j*16 + lr, kt*32 + kq*8));
    #pragma unroll
    for (int i = 0; i < 4; ++i)
      #pragma unroll
      for (int j = 0; j < 4; ++j)
        acc[i][j] = __builtin_amdgcn_mfma_f32_16x16x32_bf16(af[i], bfr[j], acc[i][j], 0, 0, 0);
  }

  #pragma unroll
  for (int i = 0; i < 4; ++i)
    #pragma unroll
    for (int j = 0; j < 4; ++j)
      #pragma unroll
      for (int r = 0; r < 4; ++r){
        int row = row0 + i*16 + kq*4 + r;
        int col = col0 + j*16 + lr;
        o_attn[(rowbase + row)*D_ + h*HD_ + col] = acc[i][j][r];
      }
}

// --------------------------------------------- gate ⊙ + rmsnorm + cast bf16
__global__ __launch_bounds__(256)
void gate_norm_kernel(const float* __restrict__ o_attn, const uint16_t* __restrict__ qkvg,
                      const float* __restrict__ norm_w, uint16_t* __restrict__ on)
{
  const int row = blockIdx.x;
  const int t = threadIdx.x;
  const int c1 = t*4, c2 = 1024 + t*4;
  const float*    orow = o_attn + (size_t)row*D_;
  const uint16_t* grow = qkvg + (size_t)row*QKVG_ + 3*D_;
  float4  o1 = *(const float4*)(orow + c1);
  float4  o2 = *(const float4*)(orow + c2);
  ushort4 g1 = *(const ushort4*)(grow + c1);
  ushort4 g2 = *(const ushort4*)(grow + c2);
  float v[8];
  v[0] = o1.x*bf2f(g1.x); v[1] = o1.y*bf2f(g1.y); v[2] = o1.z*bf2f(g1.z); v[3] = o1.w*bf2f(g1.w);
  v[4] = o2.x*bf2f(g2.x); v[5] = o2.y*bf2f(g2.y); v[6] = o2.z*bf2f(g2.z); v[7] = o2.w*bf2f(g2.w);
  float s = 0.f;
  #pragma unroll
  for (int k = 0; k < 8; ++k) s += v[k]*v[k];
  #pragma unroll
  for (int off = 32; off > 0; off >>= 1) s += __shfl_down(s, off);
  __shared__ float red[4];
  if ((t & 63) == 0) red[t >> 6] = s;
  __syncthreads();
  float total = red[0] + red[1] + red[2] + red[3];
  float scale = rsqrtf(total * (1.f/(float)D_) + 1e-6f);
  float4 w1 = *(const float4*)(norm_w + c1);
  float4 w2 = *(const float4*)(norm_w + c2);
  ushort4 b1, b2;
  b1.x = f2bf(v[0]*scale*w1.x); b1.y = f2bf(v[1]*scale*w1.y);
  b1.z = f2bf(v[2]*scale*w1.z); b1.w = f2bf(v[3]*scale*w1.w);
  b2.x = f2bf(v[4]*scale*w2.x); b2.y = f2bf(v[5]*scale*w2.y);
  b2.z = f2bf(v[6]*scale*w2.z); b2.w = f2bf(v[7]*scale*w2.w);
  *(ushort4*)(on + (size_t)row*D_ + c1) = b1;
  *(ushort4*)(on + (size_t)row*D_ + c2) = b2;
}

// =============================================================== launch
extern "C" void kernel_launch(void* const* d_in, const int* in_sizes, int n_in,
                              void* d_out, int out_size, void* d_ws, size_t ws_size,
                              hipStream_t stream) {
  const float* x         = (const float*)d_in[0];
  const float* log_decay = (const float*)d_in[1];
  const float* Wq        = (const float*)d_in[2];
  const float* Wk        = (const float*)d_in[3];
  const float* Wv        = (const float*)d_in[4];
  const float* Wo        = (const float*)d_in[5];
  const float* Wg1       = (const float*)d_in[6];
  const float* Wg2       = (const float*)d_in[7];
  const float* norm_w    = (const float*)d_in[8];
  float* out = (float*)d_out;

  // workspace layout (~160 MB with aliasing)
  uint8_t* p = (uint8_t*)d_ws;
  uint16_t* xb    = (uint16_t*)p; p += (size_t)M_*D_*2;        // reused as `on`
  uint16_t* WT    = (uint16_t*)p; p += (size_t)QKVG_*D_*2;     // reused as o_att
  uint16_t* WoT   = (uint16_t*)p; p += (size_t)D_*D_*2;
  uint16_t* Wg1b  = (uint16_t*)p; p += (size_t)D_*HD_*2;
  uint16_t* Wg2T  = (uint16_t*)p; p += (size_t)D_*HD_*2;
  uint16_t* qkvg  = (uint16_t*)p; p += (size_t)M_*QKVG_*2;     // reused as Wo partials
  uint16_t* MsumT = (uint16_t*)p; p += (size_t)NC_*B_*H_*HD_*HD_*2;
  uint16_t* StT   = (uint16_t*)p; p += (size_t)NC_*B_*H_*HD_*HD_*2;
  float*    o_att = (float*)WT;
  uint16_t* on    = xb;
  float*    part  = (float*)qkvg;   // 2 x 32MB fp32 partials (qkvg dead by then)

  // 1. cast x + all weight prep (one launch)
  cast_kernel<<<(M_*D_)/1024, 256, 0, stream>>>(x, xb);
  prep_weights<<<dim3(64, 64, 6), 256, 0, stream>>>(Wq, Wk, Wv, Wo, Wg2, Wg1,
                                                    WT, WoT, Wg2T, Wg1b);

  // 2. Wg^T = (Wg1 @ Wg2)^T into WT slice 3 (small K=128: keep 128^2 kernel)
  gemm_bt2<0,1><<<dim3(D_/128, D_/128, 1), 256, 0, stream>>>(
      Wg2T, Wg1b, WT + (size_t)3*D_*D_, D_, D_, HD_, HD_);

  // 3. fused projection: [q|k|v|gate] = act(x @ [Wq|Wk|Wv|Wg]) — single-barrier
  gemm256<3,1><<<dim3(QKVG_/256, M_/256, 1), 512, 0, stream>>>(
      xb, WT, qkvg, M_, QKVG_, D_, D_);

  // 4. attention: chunk states -> scan -> intra-chunk
  chunk_state_kernel<<<dim3(H_, B_, NC_), 256, 0, stream>>>(qkvg, log_decay, MsumT);
  scan_kernel<<<dim3(H_, B_, 8), 256, 0, stream>>>(MsumT, log_decay, StT);
  attn_kernel<<<dim3(H_, B_, NC_), 256, 0, stream>>>(qkvg, StT, log_decay, o_att);

  // 5. gate + rmsnorm + final projection (split-K=2, 256^2 kernel -> 256 wgs)
  gate_norm_kernel<<<M_, 256, 0, stream>>>(o_att, qkvg, norm_w, on);
  gemm256<0,0><<<dim3(D_/256, M_/256, 2), 512, 0, stream>>>(
      on, WoT, part, M_, D_, D_, D_/2);
  add_kernel<<<(M_*D_)/1024, 256, 0, stream>>>(part, part + (size_t)M_*D_, out);
}

// Round 6
// 400.217 us; speedup vs baseline: 1.1063x; 1.1063x over previous
//
#include <hip/hip_runtime.h>
#include <hip/hip_bf16.h>
#include <cstdint>
#include <cstddef>

#define B_   2
#define N_   2048
#define D_   2048
#define H_   16
#define HD_  128
#define C_   128
#define NC_  16
#define M_   4096   // B_*N_
#define QKVG_ 8192  // fused projection width: q|k|v|gate

typedef __attribute__((ext_vector_type(8))) short bf16x8;
typedef __attribute__((ext_vector_type(4))) float f32x4;
typedef __attribute__((ext_vector_type(16))) float f32x16;

__device__ __forceinline__ uint16_t f2bf(float f){
  __hip_bfloat16 h = __float2bfloat16(f);
  return *reinterpret_cast<uint16_t*>(&h);
}
__device__ __forceinline__ float bf2f(uint16_t u){
  union { uint32_t i; float f; } v; v.i = ((uint32_t)u) << 16; return v.f;
}

// async global->LDS, 16B per lane. LDS dest must be wave-uniform base + lane*16.
__device__ __forceinline__ void async16(const uint16_t* g, uint16_t* l){
  __builtin_amdgcn_global_load_lds(
      (const __attribute__((address_space(1))) void*)g,
      (__attribute__((address_space(3))) void*)l, 16, 0, 0);
}

// [128][128] attention-tile swizzle (unchanged, verified-correct kernels use it)
__device__ __forceinline__ int swz(int row, int c){
  return row*128 + ((((c >> 3) ^ row) & 15) << 3) + (c & 7);
}

// -------------------- all weight prep + x cast in ONE launch (grid.z = 0..6)
__global__ __launch_bounds__(256)
void prep_weights(const float* __restrict__ Wq, const float* __restrict__ Wk,
                  const float* __restrict__ Wv, const float* __restrict__ Wo,
                  const float* __restrict__ Wg2, const float* __restrict__ Wg1,
                  uint16_t* __restrict__ WT, uint16_t* __restrict__ WoT,
                  uint16_t* __restrict__ Wg2T, uint16_t* __restrict__ Wg1b,
                  const float* __restrict__ x, uint16_t* __restrict__ xb)
{
  const int z = blockIdx.z;
  const int tx = threadIdx.x & 31;
  const int ty = threadIdx.x >> 5;   // 0..7
  __shared__ uint16_t tile[32][33];

  if (z == 6){                       // cast x [4096][2048] fp32 -> bf16, float4
    const int r0 = blockIdx.y*64, c0 = blockIdx.x*32;
    const int cx = (threadIdx.x & 7)*4, ry = threadIdx.x >> 3;   // 32 rows x 8 quads
    #pragma unroll
    for (int rr = 0; rr < 2; ++rr){
      int r = r0 + ry + rr*32;
      float4 f = *(const float4*)(x + (size_t)r*D_ + c0 + cx);
      ushort4 u;
      u.x = f2bf(f.x); u.y = f2bf(f.y); u.z = f2bf(f.z); u.w = f2bf(f.w);
      *(ushort4*)(xb + (size_t)r*D_ + c0 + cx) = u;
    }
    return;
  }

  if (z == 5){                       // straight cast Wg1
    if (blockIdx.x >= 4) return;
    const int r0 = blockIdx.y*32, c0 = blockIdx.x*32;
    #pragma unroll
    for (int rr = 0; rr < 4; ++rr){
      int r = r0 + ty + rr*8;
      Wg1b[(size_t)r*HD_ + c0 + tx] = f2bf(Wg1[(size_t)r*HD_ + c0 + tx]);
    }
    return;
  }

  const float* src; uint16_t* dst; int R, Cc;
  if (z < 3)      { src = (z==0)?Wq:(z==1)?Wk:Wv; dst = WT + (size_t)z*D_*D_; R = D_; Cc = D_; }
  else if (z == 3){ src = Wo;  dst = WoT;  R = D_;  Cc = D_; }
  else            { if (blockIdx.y >= 4) return;
                    src = Wg2; dst = Wg2T; R = HD_; Cc = D_; }

  const int r0 = blockIdx.y*32, c0 = blockIdx.x*32;
  #pragma unroll
  for (int rr = 0; rr < 4; ++rr){
    int r = ty + rr*8;
    tile[r][tx] = f2bf(src[(size_t)(r0 + r)*Cc + c0 + tx]);
  }
  __syncthreads();
  #pragma unroll
  for (int rr = 0; rr < 4; ++rr){
    int r = ty + rr*8;
    dst[(size_t)(c0 + r)*R + r0 + tx] = tile[tx][r];
  }
}

// ---------------------- GEMM v2: 128x128, 4 waves (small-K Wg GEMM + Wo GEMM)
// For Wo: grid z=1, klen=K, OUTBF=0 -> writes fp32 directly (offset 0), no
// split-K partials / add kernel (saves 96 MB of HBM round-trip).
template<int ACT, int OUTBF>
__global__ __launch_bounds__(256)
void gemm_bt2(const uint16_t* __restrict__ A, const uint16_t* __restrict__ Bt,
              void* __restrict__ Cout, int M, int Ncols, int K, int klen)
{
  __shared__ __align__(16) uint16_t As[128*64];
  __shared__ __align__(16) uint16_t Bs[128*64];
  const int t    = threadIdx.x;
  const int lane = t & 63, wave = t >> 6;
  const int wm = wave >> 1, wn = wave & 1;
  const int row0 = wm*64, col0 = wn*64;
  const int lm = lane & 31, lh = lane >> 5;

  const uint16_t* Ap = A  + (size_t)(blockIdx.y*128)*K;
  const uint16_t* Bp = Bt + (size_t)(blockIdx.x*128)*K;
  const int kbeg = blockIdx.z * klen;

  f32x16 acc[2][2];
  #pragma unroll
  for (int i = 0; i < 2; ++i)
    #pragma unroll
    for (int j = 0; j < 2; ++j)
      #pragma unroll
      for (int r = 0; r < 16; ++r) acc[i][j][r] = 0.f;

  const int srow = t >> 3;
  const int gch  = (t & 7) ^ (srow & 7);
  const size_t aoff0 = (size_t)srow*K + gch*8;

  for (int k0 = kbeg; k0 < kbeg + klen; k0 += 64){
    #pragma unroll
    for (int c = 0; c < 4; ++c){
      async16(Ap + (size_t)(c*32)*K + aoff0 + k0, As + c*2048 + t*8);
      async16(Bp + (size_t)(c*32)*K + aoff0 + k0, Bs + c*2048 + t*8);
    }
    __syncthreads();
    #pragma unroll
    for (int kh = 0; kh < 4; ++kh){
      bf16x8 af[2], bfr[2];
      const int ch = kh*2 + lh;
      #pragma unroll
      for (int i = 0; i < 2; ++i){
        int r = row0 + i*32 + lm;
        af[i] = *(const bf16x8*)(As + r*64 + ((ch ^ (r & 7)) << 3));
      }
      #pragma unroll
      for (int j = 0; j < 2; ++j){
        int r = col0 + j*32 + lm;
        bfr[j] = *(const bf16x8*)(Bs + r*64 + ((ch ^ (r & 7)) << 3));
      }
      #pragma unroll
      for (int i = 0; i < 2; ++i)
        #pragma unroll
        for (int j = 0; j < 2; ++j)
          acc[i][j] = __builtin_amdgcn_mfma_f32_32x32x16_bf16(af[i], bfr[j], acc[i][j], 0, 0, 0);
    }
    __syncthreads();
  }

  const int mode = (ACT == 3) ? ((blockIdx.x < 48) ? 1 : 2) : ACT;
  uint16_t* outb = (uint16_t*)Cout;
  float*    outf = (float*)Cout + (OUTBF ? 0 : (size_t)blockIdx.z*M*Ncols);
  #pragma unroll
  for (int i = 0; i < 2; ++i){
    #pragma unroll
    for (int j = 0; j < 2; ++j){
      #pragma unroll
      for (int r = 0; r < 16; ++r){
        int row = blockIdx.y*128 + row0 + i*32 + (r & 3) + 8*(r >> 2) + 4*lh;
        int col = blockIdx.x*128 + col0 + j*32 + lm;
        float v = acc[i][j][r];
        if (mode == 1)      v = v / (1.f + __expf(-v));
        else if (mode == 2) v = 1.f / (1.f + __expf(-v));
        size_t off = (size_t)row*Ncols + col;
        if (OUTBF) outb[off] = f2bf(v);
        else       outf[off] = v;
      }
    }
  }
}

// ============================================================ GEMM v7: 256x256
// R4 ring-4 structure + one-phase READ-AHEAD into a second register set:
//   - BK=32 K-steps, ring-of-4 LDS buffers, staging 3 steps ahead (A-half at
//     P0, B-half at P1 of each step).
//   - 8 waves 2M x 4N (wave tile 128x64), 32x32x16 MFMA, acc[4][2] f32x16.
//   - Per phase: issue 6 ds_read for the NEXT phase's frags, then a COUNTED
//     s_waitcnt lgkmcnt(6) that drains only the PREVIOUS phase's reads (in-
//     order DS retire) -> the wait has a full phase (~540 cyc) of slack.
//   - ONE s_barrier per K-step (was 4 in R4); counted vmcnt(4) per step.
// Hazard ledger (enumerated):
//   lgkm: at each wait, outstanding = 6 older (consumed now) + 6 newer ->
//     lgkm(6) retires exactly the older set. Last phase issues no reads ->
//     lgkm(0).
//   RAW(stage): end-of-step-kt vmcnt(4) leaves only tile kt+3 (staged this
//     step) in flight -> certifies tile kt+2, which is read-ahead-read at
//     P(kt+1,1) and fully read at step kt+2. Prologue: stage 0,1,2; vmcnt(4)
//     certifies tiles 0 AND 1 (P(0,1) read-ahead needs buf1). Tail: vmcnt(0)
//     at kt==NTK-3.
//   WAR: stage(kt+3) -> buf[kt-1]; its last reads (S1 slice, issued P(kt-1,0))
//     are drained by P(kt-1,1)'s lgkm(6) (oldest-first), then the step-end
//     barrier orders all waves before any stage in step kt.
//   Read-ahead P(kt,1) reads buf[kt+1]: certified end of step kt-1; stages
//     during step kt target buf[kt-1] != buf[kt+1]. Safe.
template<int ACT, int OUTBF>
__global__ __launch_bounds__(512, 2)
void gemm256(const uint16_t* __restrict__ A, const uint16_t* __restrict__ Bt,
             void* __restrict__ Cout, int M, int Ncols, int K, int klen)
{
  __shared__ __align__(16) uint16_t As[4*256*32];   // 64 KiB: ring of 4
  __shared__ __align__(16) uint16_t Bs[4*256*32];   // 64 KiB
  const int t    = threadIdx.x;
  const int lane = t & 63, wave = t >> 6;
  const int wm = wave >> 2, wn = wave & 3;          // 2M x 4N wave grid
  const int lm = lane & 31, lh = lane >> 5;
  const int sel = (lm >> 1) & 3;

  // element offsets inside one 8192-elem buffer: row*32 + slot*8
  int arow[4], brow[2], sl[2];
  #pragma unroll
  for (int m = 0; m < 4; ++m) arow[m] = (wm*128 + m*32 + lm)*32;
  #pragma unroll
  for (int n = 0; n < 2; ++n) brow[n] = (wn*64 + n*32 + lm)*32;
  #pragma unroll
  for (int kk = 0; kk < 2; ++kk) sl[kk] = ((kk*2 + lh) ^ sel) << 3;

  const uint16_t* Ap = A  + (size_t)(blockIdx.y*256)*K;
  const uint16_t* Bp = Bt + (size_t)(blockIdx.x*256)*K;
  const int kbeg = blockIdx.z*klen;
  const int NTK  = klen >> 5;                       // BK=32 K-steps (NTK >= 4)

  // staging map: thread t fills LDS elems t*8..t*8+7 (row t>>2, slot t&3);
  // global chunk pre-swizzled: gch = slot ^ ((row>>1)&3)  (rule #21).
  const int gch  = (t & 3) ^ ((t >> 3) & 3);
  const size_t srcoff = (size_t)(t >> 2)*K + gch*8;
  const int ldst = t*8;

  f32x16 acc[4][2];
  #pragma unroll
  for (int m = 0; m < 4; ++m)
    #pragma unroll
    for (int n = 0; n < 2; ++n)
      #pragma unroll
      for (int r = 0; r < 16; ++r) acc[m][n][r] = 0.f;

  auto stageA = [&](int j){        // A of K-step j -> buf j&3 (2 stmts, 16 KiB)
    const size_t ko = (size_t)kbeg + (size_t)j*32;
    uint16_t* d = As + (j & 3)*8192 + ldst;
    async16(Ap + srcoff + ko, d);
    async16(Ap + (size_t)128*K + srcoff + ko, d + 4096);
  };
  auto stageB = [&](int j){
    const size_t ko = (size_t)kbeg + (size_t)j*32;
    uint16_t* d = Bs + (j & 3)*8192 + ldst;
    async16(Bp + srcoff + ko, d);
    async16(Bp + (size_t)128*K + srcoff + ko, d + 4096);
  };

  // prologue: stage K-steps 0..2; vmcnt(4) certifies steps 0 AND 1.
  stageA(0); stageB(0);
  stageA(1); stageB(1);
  stageA(2); stageB(2);
  asm volatile("s_waitcnt vmcnt(4)" ::: "memory");
  __builtin_amdgcn_s_barrier();
  asm volatile("" ::: "memory");

  bf16x8 af0[4], bf0[2], af1[4], bf1[2];
  #pragma unroll
  for (int m = 0; m < 4; ++m) af0[m] = *(const bf16x8*)(As + arow[m] + sl[0]);
  #pragma unroll
  for (int n = 0; n < 2; ++n) bf0[n] = *(const bf16x8*)(Bs + brow[n] + sl[0]);

  for (int kt = 0; kt < NTK; ++kt){
    const uint16_t* Ac = As + (kt & 3)*8192;
    const uint16_t* Bc = Bs + (kt & 3)*8192;
    const uint16_t* An = As + ((kt + 1) & 3)*8192;
    const uint16_t* Bn = Bs + ((kt + 1) & 3)*8192;

    // ---- P0: issue reads for S1 (cur, kk1); stage A(kt+3); wait S0; MFMA S0
    #pragma unroll
    for (int m = 0; m < 4; ++m) af1[m] = *(const bf16x8*)(Ac + arow[m] + sl[1]);
    #pragma unroll
    for (int n = 0; n < 2; ++n) bf1[n] = *(const bf16x8*)(Bc + brow[n] + sl[1]);
    if (kt + 3 < NTK) stageA(kt + 3);
    asm volatile("s_waitcnt lgkmcnt(6)" ::: "memory");   // drains S0's reads only
    __builtin_amdgcn_sched_barrier(0);                   // rule #18
    __builtin_amdgcn_s_setprio(1);
    #pragma unroll
    for (int m = 0; m < 4; ++m)
      #pragma unroll
      for (int n = 0; n < 2; ++n)
        acc[m][n] = __builtin_amdgcn_mfma_f32_32x32x16_bf16(af0[m], bf0[n], acc[m][n], 0, 0, 0);
    __builtin_amdgcn_s_setprio(0);

    // ---- P1: issue reads for next S0 (next buf, kk0); stage B(kt+3); wait S1;
    //          MFMA S1; counted vmcnt; ONE barrier per step.
    if (kt + 1 < NTK){
      #pragma unroll
      for (int m = 0; m < 4; ++m) af0[m] = *(const bf16x8*)(An + arow[m] + sl[0]);
      #pragma unroll
      for (int n = 0; n < 2; ++n) bf0[n] = *(const bf16x8*)(Bn + brow[n] + sl[0]);
    }
    if (kt + 3 < NTK) stageB(kt + 3);
    if (kt + 1 < NTK) asm volatile("s_waitcnt lgkmcnt(6)" ::: "memory");
    else              asm volatile("s_waitcnt lgkmcnt(0)" ::: "memory");
    __builtin_amdgcn_sched_barrier(0);
    __builtin_amdgcn_s_setprio(1);
    #pragma unroll
    for (int m = 0; m < 4; ++m)
      #pragma unroll
      for (int n = 0; n < 2; ++n)
        acc[m][n] = __builtin_amdgcn_mfma_f32_32x32x16_bf16(af1[m], bf1[n], acc[m][n], 0, 0, 0);
    __builtin_amdgcn_s_setprio(0);

    if (kt + 3 < NTK)       asm volatile("s_waitcnt vmcnt(4)" ::: "memory");
    else if (kt + 3 == NTK) asm volatile("s_waitcnt vmcnt(0)" ::: "memory");
    __builtin_amdgcn_s_barrier();
    asm volatile("" ::: "memory");
  }

  // epilogue. 32x32 C/D layout: col = lane&31, row = (r&3) + 8*(r>>2) + 4*lh
  const int mode = (ACT == 3) ? (((blockIdx.x << 8) < Ncols - 2048) ? 1 : 2) : ACT;
  uint16_t* outb = (uint16_t*)Cout;
  float*    outf = (float*)Cout + (OUTBF ? 0 : (size_t)blockIdx.z*M*Ncols);
  #pragma unroll
  for (int m = 0; m < 4; ++m){
    #pragma unroll
    for (int n = 0; n < 2; ++n){
      #pragma unroll
      for (int r = 0; r < 16; ++r){
        int row = blockIdx.y*256 + wm*128 + m*32 + (r & 3) + 8*(r >> 2) + 4*lh;
        int col = blockIdx.x*256 + wn*64  + n*32 + lm;
        float v = acc[m][n][r];
        if (mode == 1)      v = v / (1.f + __expf(-v));
        else if (mode == 2) v = 1.f / (1.f + __expf(-v));
        size_t off = (size_t)row*Ncols + col;
        if (OUTBF) outb[off] = f2bf(v);
        else       outf[off] = v;
      }
    }
  }
}

// ---------------------------------------------- per-chunk state contribution
__global__ __launch_bounds__(256)
void chunk_state_kernel(const uint16_t* __restrict__ qkvg,
                        const float* __restrict__ log_decay, uint16_t* __restrict__ MsumT)
{
  __shared__ __align__(16) uint16_t vT[128*128];
  __shared__ __align__(16) uint16_t kT[128*128];
  const int h = blockIdx.x, b = blockIdx.y, ic = blockIdx.z;
  const int t    = threadIdx.x;
  const int lane = t & 63, wave = t >> 6;
  const int wm = wave >> 1, wn = wave & 1;
  const int e0 = wm*64, d0 = wn*64;
  const int lr = lane & 15, kq = lane >> 4;
  const float ld = log_decay[h];
  const size_t rowbase = (size_t)b*N_ + (size_t)ic*C_;
  const uint16_t* kb = qkvg + (size_t)D_;
  const uint16_t* vb = qkvg + (size_t)2*D_;

  #pragma unroll 4
  for (int it = 0; it < 64; ++it){
    int idx = t + it*256;
    int j = idx >> 7, e = idx & 127;
    uint16_t vv = vb[(rowbase + j)*QKVG_ + h*HD_ + e];
    float kf = bf2f(kb[(rowbase + j)*QKVG_ + h*HD_ + e]) * __expf(ld * (float)(C_ - 1 - j));
    vT[swz(e, j)] = vv;
    kT[swz(e, j)] = f2bf(kf);
  }
  __syncthreads();

  const f32x4 zero = {0.f, 0.f, 0.f, 0.f};
  f32x4 acc[4][4];
  #pragma unroll
  for (int i = 0; i < 4; ++i)
    #pragma unroll
    for (int j = 0; j < 4; ++j) acc[i][j] = zero;

  #pragma unroll
  for (int kt = 0; kt < 4; ++kt){
    bf16x8 af[4], bfr[4];
    #pragma unroll
    for (int i = 0; i < 4; ++i)
      af[i]  = *(const bf16x8*)(vT + swz(e0 + i*16 + lr, kt*32 + kq*8));
    #pragma unroll
    for (int j = 0; j < 4; ++j)
      bfr[j] = *(const bf16x8*)(kT + swz(d0 + j*16 + lr, kt*32 + kq*8));
    #pragma unroll
    for (int i = 0; i < 4; ++i)
      #pragma unroll
      for (int j = 0; j < 4; ++j)
        acc[i][j] = __builtin_amdgcn_mfma_f32_16x16x32_bf16(af[i], bfr[j], acc[i][j], 0, 0, 0);
  }

  uint16_t* Mout = MsumT + (((size_t)ic*B_ + b)*H_ + h)*(size_t)(HD_*HD_);
  #pragma unroll
  for (int i = 0; i < 4; ++i)
    #pragma unroll
    for (int j = 0; j < 4; ++j)
      #pragma unroll
      for (int r = 0; r < 4; ++r)
        Mout[(size_t)(e0 + i*16 + kq*4 + r)*HD_ + d0 + j*16 + lr] = f2bf(acc[i][j][r]);
}

// -------------------------------------------------- inter-chunk state scan
__global__ __launch_bounds__(256)
void scan_kernel(const uint16_t* __restrict__ MsumT, const float* __restrict__ log_decay,
                 uint16_t* __restrict__ StT)
{
  const int h = blockIdx.x, b = blockIdx.y;
  const float ld = log_decay[h];
  const float dS = __expf(ld * (float)C_);
  const int base_e = blockIdx.z*2048;
  float cur[8];
  #pragma unroll
  for (int r = 0; r < 8; ++r) cur[r] = 0.f;
  for (int i = 0; i < NC_; ++i){
    const size_t base = (((size_t)i*B_ + b)*H_ + h)*(size_t)(HD_*HD_) + base_e;
    #pragma unroll
    for (int r = 0; r < 8; ++r){
      int idx = threadIdx.x + r*256;
      StT[base + idx] = f2bf(cur[r]);
      cur[r] = cur[r]*dS + bf2f(MsumT[base + idx]);
    }
  }
}

// ------------------------------------------------------ intra-chunk attention
__global__ __launch_bounds__(256)
void attn_kernel(const uint16_t* __restrict__ qkvg, const uint16_t* __restrict__ StT,
                 const float* __restrict__ log_decay, float* __restrict__ o_attn)
{
  __shared__ __align__(16) uint16_t Ps[128*128];
  __shared__ __align__(16) uint16_t vT[128*128];
  const int h = blockIdx.x, b = blockIdx.y, ic = blockIdx.z;
  const int t    = threadIdx.x;
  const int lane = t & 63, wave = t >> 6;
  const int wm = wave >> 1, wn = wave & 1;
  const int row0 = wm*64, col0 = wn*64;
  const int lr = lane & 15, kq = lane >> 4;
  const float ld = log_decay[h];
  const size_t rowbase = (size_t)b*N_ + (size_t)ic*C_;
  const uint16_t* qb = qkvg;
  const uint16_t* kb = qkvg + (size_t)D_;
  const uint16_t* vb = qkvg + (size_t)2*D_;

  #pragma unroll 4
  for (int it = 0; it < 64; ++it){
    int idx = t + it*256;
    int j = idx >> 7, e = idx & 127;
    vT[swz(e, j)] = vb[(rowbase + j)*QKVG_ + h*HD_ + e];
  }

  const f32x4 zero = {0.f, 0.f, 0.f, 0.f};
  f32x4 acc[4][4];
  #pragma unroll
  for (int i = 0; i < 4; ++i)
    #pragma unroll
    for (int j = 0; j < 4; ++j) acc[i][j] = zero;

  // phase A: P = (q @ k^T) ∘ Dm
  #pragma unroll
  for (int kt = 0; kt < 4; ++kt){
    bf16x8 af[4], bfr[4];
    #pragma unroll
    for (int i = 0; i < 4; ++i)
      af[i]  = *(const bf16x8*)(qb + (rowbase + row0 + i*16 + lr)*QKVG_ + h*HD_ + kt*32 + kq*8);
    #pragma unroll
    for (int j = 0; j < 4; ++j)
      bfr[j] = *(const bf16x8*)(kb + (rowbase + col0 + j*16 + lr)*QKVG_ + h*HD_ + kt*32 + kq*8);
    #pragma unroll
    for (int i = 0; i < 4; ++i)
      #pragma unroll
      for (int j = 0; j < 4; ++j)
        acc[i][j] = __builtin_amdgcn_mfma_f32_16x16x32_bf16(af[i], bfr[j], acc[i][j], 0, 0, 0);
  }
  #pragma unroll
  for (int i = 0; i < 4; ++i)
    #pragma unroll
    for (int j = 0; j < 4; ++j)
      #pragma unroll
      for (int r = 0; r < 4; ++r){
        int row = row0 + i*16 + kq*4 + r;
        int col = col0 + j*16 + lr;
        int dlt = row - col;
        float f = (dlt >= 0) ? __expf(ld * (float)dlt) : 0.f;
        Ps[swz(row, col)] = f2bf(acc[i][j][r] * f);
      }

  // phase B1: o2 = q @ S_start
  #pragma unroll
  for (int i = 0; i < 4; ++i)
    #pragma unroll
    for (int j = 0; j < 4; ++j) acc[i][j] = zero;
  const uint16_t* Sb = StT + (((size_t)ic*B_ + b)*H_ + h)*(size_t)(HD_*HD_);
  #pragma unroll
  for (int kt = 0; kt < 4; ++kt){
    bf16x8 af[4], bfr[4];
    #pragma unroll
    for (int i = 0; i < 4; ++i)
      af[i]  = *(const bf16x8*)(qb + (rowbase + row0 + i*16 + lr)*QKVG_ + h*HD_ + kt*32 + kq*8);
    #pragma unroll
    for (int j = 0; j < 4; ++j)
      bfr[j] = *(const bf16x8*)(Sb + (size_t)(col0 + j*16 + lr)*HD_ + kt*32 + kq*8);
    #pragma unroll
    for (int i = 0; i < 4; ++i)
      #pragma unroll
      for (int j = 0; j < 4; ++j)
        acc[i][j] = __builtin_amdgcn_mfma_f32_16x16x32_bf16(af[i], bfr[j], acc[i][j], 0, 0, 0);
  }
  #pragma unroll
  for (int i = 0; i < 4; ++i)
    #pragma unroll
    for (int r = 0; r < 4; ++r){
      float dqv = __expf(ld * (float)(row0 + i*16 + kq*4 + r + 1));
      #pragma unroll
      for (int j = 0; j < 4; ++j) acc[i][j][r] *= dqv;
    }

  __syncthreads();

  // phase B2: o += P @ v
  #pragma unroll
  for (int kt = 0; kt < 4; ++kt){
    bf16x8 af[4], bfr[4];
    #pragma unroll
    for (int i = 0; i < 4; ++i)
      af[i]  = *(const bf16x8*)(Ps + swz(row0 + i*16 + lr, kt*32 + kq*8));
    #pragma unroll
    for (int j = 0; j < 4; ++j)
      bfr[j] = *(const bf16x8*)(vT + swz(col0 + j*16 + lr, kt*32 + kq*8));
    #pragma unroll
    for (int i = 0; i < 4; ++i)
      #pragma unroll
      for (int j = 0; j < 4; ++j)
        acc[i][j] = __builtin_amdgcn_mfma_f32_16x16x32_bf16(af[i], bfr[j], acc[i][j], 0, 0, 0);
  }

  #pragma unroll
  for (int i = 0; i < 4; ++i)
    #pragma unroll
    for (int j = 0; j < 4; ++j)
      #pragma unroll
      for (int r = 0; r < 4; ++r){
        int row = row0 + i*16 + kq*4 + r;
        int col = col0 + j*16 + lr;
        o_attn[(rowbase + row)*D_ + h*HD_ + col] = acc[i][j][r];
      }
}

// --------------------------------------------- gate ⊙ + rmsnorm + cast bf16
__global__ __launch_bounds__(256)
void gate_norm_kernel(const float* __restrict__ o_attn, const uint16_t* __restrict__ qkvg,
                      const float* __restrict__ norm_w, uint16_t* __restrict__ on)
{
  const int row = blockIdx.x;
  const int t = threadIdx.x;
  const int c1 = t*4, c2 = 1024 + t*4;
  const float*    orow = o_attn + (size_t)row*D_;
  const uint16_t* grow = qkvg + (size_t)row*QKVG_ + 3*D_;
  float4  o1 = *(const float4*)(orow + c1);
  float4  o2 = *(const float4*)(orow + c2);
  ushort4 g1 = *(const ushort4*)(grow + c1);
  ushort4 g2 = *(const ushort4*)(grow + c2);
  float v[8];
  v[0] = o1.x*bf2f(g1.x); v[1] = o1.y*bf2f(g1.y); v[2] = o1.z*bf2f(g1.z); v[3] = o1.w*bf2f(g1.w);
  v[4] = o2.x*bf2f(g2.x); v[5] = o2.y*bf2f(g2.y); v[6] = o2.z*bf2f(g2.z); v[7] = o2.w*bf2f(g2.w);
  float s = 0.f;
  #pragma unroll
  for (int k = 0; k < 8; ++k) s += v[k]*v[k];
  #pragma unroll
  for (int off = 32; off > 0; off >>= 1) s += __shfl_down(s, off);
  __shared__ float red[4];
  if ((t & 63) == 0) red[t >> 6] = s;
  __syncthreads();
  float total = red[0] + red[1] + red[2] + red[3];
  float scale = rsqrtf(total * (1.f/(float)D_) + 1e-6f);
  float4 w1 = *(const float4*)(norm_w + c1);
  float4 w2 = *(const float4*)(norm_w + c2);
  ushort4 b1, b2;
  b1.x = f2bf(v[0]*scale*w1.x); b1.y = f2bf(v[1]*scale*w1.y);
  b1.z = f2bf(v[2]*scale*w1.z); b1.w = f2bf(v[3]*scale*w1.w);
  b2.x = f2bf(v[4]*scale*w2.x); b2.y = f2bf(v[5]*scale*w2.y);
  b2.z = f2bf(v[6]*scale*w2.z); b2.w = f2bf(v[7]*scale*w2.w);
  *(ushort4*)(on + (size_t)row*D_ + c1) = b1;
  *(ushort4*)(on + (size_t)row*D_ + c2) = b2;
}

// =============================================================== launch
extern "C" void kernel_launch(void* const* d_in, const int* in_sizes, int n_in,
                              void* d_out, int out_size, void* d_ws, size_t ws_size,
                              hipStream_t stream) {
  const float* x         = (const float*)d_in[0];
  const float* log_decay = (const float*)d_in[1];
  const float* Wq        = (const float*)d_in[2];
  const float* Wk        = (const float*)d_in[3];
  const float* Wv        = (const float*)d_in[4];
  const float* Wo        = (const float*)d_in[5];
  const float* Wg1       = (const float*)d_in[6];
  const float* Wg2       = (const float*)d_in[7];
  const float* norm_w    = (const float*)d_in[8];
  float* out = (float*)d_out;

  // workspace layout (~160 MB with aliasing)
  uint8_t* p = (uint8_t*)d_ws;
  uint16_t* xb    = (uint16_t*)p; p += (size_t)M_*D_*2;        // reused as `on`
  uint16_t* WT    = (uint16_t*)p; p += (size_t)QKVG_*D_*2;     // reused as o_att
  uint16_t* WoT   = (uint16_t*)p; p += (size_t)D_*D_*2;
  uint16_t* Wg1b  = (uint16_t*)p; p += (size_t)D_*HD_*2;
  uint16_t* Wg2T  = (uint16_t*)p; p += (size_t)D_*HD_*2;
  uint16_t* qkvg  = (uint16_t*)p; p += (size_t)M_*QKVG_*2;
  uint16_t* MsumT = (uint16_t*)p; p += (size_t)NC_*B_*H_*HD_*HD_*2;
  uint16_t* StT   = (uint16_t*)p; p += (size_t)NC_*B_*H_*HD_*HD_*2;
  float*    o_att = (float*)WT;
  uint16_t* on    = xb;

  // 1. all weight prep + x cast in ONE launch (z = 0..6)
  prep_weights<<<dim3(64, 64, 7), 256, 0, stream>>>(Wq, Wk, Wv, Wo, Wg2, Wg1,
                                                    WT, WoT, Wg2T, Wg1b, x, xb);

  // 2. Wg^T = (Wg1 @ Wg2)^T into WT slice 3 (small K=128: 128^2 kernel)
  gemm_bt2<0,1><<<dim3(D_/128, D_/128, 1), 256, 0, stream>>>(
      Wg2T, Wg1b, WT + (size_t)3*D_*D_, D_, D_, HD_, HD_);

  // 3. fused projection: [q|k|v|gate] = act(x @ [Wq|Wk|Wv|Wg]) — v7 read-ahead
  gemm256<3,1><<<dim3(QKVG_/256, M_/256, 1), 512, 0, stream>>>(
      xb, WT, qkvg, M_, QKVG_, D_, D_);

  // 4. attention: chunk states -> scan -> intra-chunk
  chunk_state_kernel<<<dim3(H_, B_, NC_), 256, 0, stream>>>(qkvg, log_decay, MsumT);
  scan_kernel<<<dim3(H_, B_, 8), 256, 0, stream>>>(MsumT, log_decay, StT);
  attn_kernel<<<dim3(H_, B_, NC_), 256, 0, stream>>>(qkvg, StT, log_decay, o_att);

  // 5. gate + rmsnorm + final projection: single-pass 128^2 GEMM, fp32 direct
  //    to out (no split-K partials, no add kernel — saves 96 MB round-trip)
  gate_norm_kernel<<<M_, 256, 0, stream>>>(o_att, qkvg, norm_w, on);
  gemm_bt2<0,0><<<dim3(D_/128, M_/128, 1), 256, 0, stream>>>(
      on, WoT, out, M_, D_, D_, D_);
}